// Round 15
// baseline (266.264 us; speedup 1.0000x reference)
//
#include <hip/hip_runtime.h>

#define NNODES 50000
#define NEDGES 800000
#define HIDDIM 256
#define NB_SCAN 196   // ceil(NNODES/256)
#define NCHUNK  1563  // ceil(NNODES/32)
#define GEMMB   256   // persistent blocks (1 per CU)
#define CSRT    512   // threads in fused kernel

constexpr float kAlpha = 0.1f;
constexpr float kBnEps = 1e-5f;
constexpr float kBeta  = 0.40546510810816438198f;   // log(1.5)

typedef __attribute__((ext_vector_type(8))) short  bf16x8;   // 8 bf16 in 4 VGPRs
typedef __attribute__((ext_vector_type(4))) float  f32x4;

typedef __attribute__((address_space(1))) const unsigned int gu32;  // global
typedef __attribute__((address_space(3))) unsigned int       lu32;  // LDS

static __device__ __forceinline__ unsigned short f2bf(float f) {
  unsigned u = __float_as_uint(f);
  u = (u + 0x7FFFu + ((u >> 16) & 1u)) >> 16;      // RTNE
  return (unsigned short)u;
}
static __device__ __forceinline__ float bf2f(unsigned short h) {
  return __uint_as_float(((unsigned)h) << 16);
}

// grid barrier: all blocks co-resident (256 blocks, 1/CU) -> spin is safe.
// counters zeroed by hipMemsetAsync each call (graph-deterministic).
static __device__ __forceinline__ void gridbar(int* c, int nblk) {
  __syncthreads();
  if (threadIdx.x == 0) {
    __hip_atomic_fetch_add(c, 1, __ATOMIC_ACQ_REL, __HIP_MEMORY_SCOPE_AGENT);
    while (__hip_atomic_load(c, __ATOMIC_ACQUIRE, __HIP_MEMORY_SCOPE_AGENT) < nblk) {
      __builtin_amdgcn_s_sleep(8);
    }
  }
  __syncthreads();
}

// ---------------------------------------------------------------------------
// prep: weight transposes (fp32 [k][n] -> bf16 [n][k]) + zero BN stats
// ---------------------------------------------------------------------------
__global__ __launch_bounds__(256) void prep_k(const float* __restrict__ W_pre,
                                              const float* __restrict__ W_op,
                                              unsigned short* __restrict__ wpre_t,
                                              unsigned short* __restrict__ wop_t,
                                              float* __restrict__ colsum,
                                              float* __restrict__ colsumsq) {
  int b = blockIdx.x, t = threadIdx.x;
  if (b < 256) {
    wpre_t[b * 256 + t] = f2bf(W_pre[t * 256 + b]);
    if (b == 0) { colsum[t] = 0.f; colsumsq[t] = 0.f; }
  } else {
    int n = b - 256;
    wop_t[n * 256 + t] = f2bf(W_op[t * 256 + n]);
  }
}

// ---------------------------------------------------------------------------
// FUSED: CSR build (hist -> scan -> fill) + persistent GEMM1, one dispatch.
// 256 blocks x 512 threads, 160 KB LDS. B preloaded (issued in phase 0),
// 4 grid barriers; fill embedded in the first two GEMM chunk iterations so
// its atomics hide under MFMA / A-prefetch.
// GEMM1: h = s1 @ W_pre (bf16 out) + column sum/sumsq (reg-accumulated).
// ---------------------------------------------------------------------------
__global__ __launch_bounds__(512) void csr_gemm1_k(
    const float* __restrict__ s1,
    const unsigned short* __restrict__ wpre_t,
    unsigned short* __restrict__ hbf,
    float* __restrict__ colsum,
    float* __restrict__ colsumsq,
    const int* __restrict__ ei,
    int* __restrict__ deg,
    int* __restrict__ rowptr,
    int* __restrict__ cursor,
    int* __restrict__ esrc,
    int* __restrict__ blocksum,
    int* __restrict__ barc) {
  __shared__ __align__(16) unsigned short Bl[256 * 256];   // 128 KB
  __shared__ __align__(16) unsigned short Al[2][32 * 256]; // 2 x 16 KB
  int* shA = (int*)&Al[0][0];        // scan scratch alias (2 KB, used pre-GEMM)
  int* shB = shA + 256;

  const int b    = blockIdx.x;
  const int t    = threadIdx.x;      // 0..511
  const int lane = t & 63;
  const int wid  = t >> 6;           // 0..7
  const int wr   = wid >> 2;         // row group 0/1
  const int wc   = wid & 3;          // col group 0..3

  // ---- phase 0: issue B preload + zero deg ----
  {
    const int lrow = lane >> 5, lchk = lane & 31;
#pragma unroll
    for (int c = 0; c < 16; ++c) {
      int issue = wid * 16 + c;
      int row = issue * 2 + lrow;
      int srcoff = (lchk * 16) ^ ((row & 7) << 4);
      const char* g = (const char*)wpre_t + (size_t)row * 512 + srcoff;
      char* l = (char*)Bl + issue * 1024 + lane * 16;
      __builtin_amdgcn_global_load_lds((gu32*)g, (lu32*)l, 16, 0, 0);
    }
  }
  for (int i = b * CSRT + t; i < NNODES; i += GEMMB * CSRT)
    __hip_atomic_store(&deg[i], 0, __ATOMIC_RELAXED, __HIP_MEMORY_SCOPE_AGENT);
  gridbar(&barc[0], GEMMB);

  // ---- phase 1: degree histogram ----
  {
    const int4* dst4 = (const int4*)(ei + NEDGES);
    const int n4 = NEDGES / 4;
    for (int i = b * CSRT + t; i < n4; i += GEMMB * CSRT) {
      int4 d = dst4[i];
      atomicAdd(&deg[d.x], 1);
      atomicAdd(&deg[d.y], 1);
      atomicAdd(&deg[d.z], 1);
      atomicAdd(&deg[d.w], 1);
    }
  }
  gridbar(&barc[1], GEMMB);

  // ---- phase 2: per-block exclusive scan (blocks 0..195, threads 0..255) ----
  int myv = 0;
  if (b < NB_SCAN && t < 256) {
    int idx = b * 256 + t;
    myv = (idx < NNODES)
        ? __hip_atomic_load(&deg[idx], __ATOMIC_RELAXED, __HIP_MEMORY_SCOPE_AGENT) : 0;
    shA[t] = myv;
  }
  __syncthreads();
  for (int off = 1; off < 256; off <<= 1) {
    int x = (t < 256 && t >= off) ? shA[t - off] : 0;
    __syncthreads();
    if (t < 256) shA[t] += x;
    __syncthreads();
  }
  if (b < NB_SCAN && t < 256) {
    int idx = b * 256 + t;
    if (idx < NNODES) rowptr[idx] = shA[t] - myv;     // local exclusive
    if (t == 255)
      __hip_atomic_store(&blocksum[b], shA[255], __ATOMIC_RELAXED, __HIP_MEMORY_SCOPE_AGENT);
  }
  gridbar(&barc[2], GEMMB);

  // ---- phase 3: every block scans the 196 block sums; finalize rowptr/cursor ----
  if (t < 256) {
    int v = (t < NB_SCAN)
          ? __hip_atomic_load(&blocksum[t], __ATOMIC_RELAXED, __HIP_MEMORY_SCOPE_AGENT) : 0;
    shA[t] = v; shB[t] = v;
  }
  __syncthreads();
  for (int off = 1; off < 256; off <<= 1) {
    int x = (t < 256 && t >= off) ? shA[t - off] : 0;
    __syncthreads();
    if (t < 256) shA[t] += x;
    __syncthreads();
  }
  if (b < NB_SCAN && t < 256) {
    int boff = shA[b] - shB[b];                       // exclusive block offset
    int idx = b * 256 + t;
    if (idx < NNODES) {
      int rp = rowptr[idx] + boff;
      rowptr[idx] = rp;
      __hip_atomic_store(&cursor[idx], rp, __ATOMIC_RELAXED, __HIP_MEMORY_SCOPE_AGENT);
    }
    if (b == NB_SCAN - 1 && t == 0) rowptr[NNODES] = shA[NB_SCAN - 1];
  }
  gridbar(&barc[3], GEMMB);

  // ---- phase 4: persistent GEMM1 with fill embedded in first 2 iterations ----
  float spart[4] = {0.f, 0.f, 0.f, 0.f};
  float qpart[4] = {0.f, 0.f, 0.f, 0.f};

  auto stageA = [&](int buf, int chunk) {
    const int row = t >> 4;            // 0..31
    const int seg = t & 15;            // 16 fp32 each
    const int arow = chunk * 32 + row;
    const float* src = s1 + (size_t)arow * 256 + seg * 16;
    bf16x8 v0 = {}, v1 = {};
    if (arow < NNODES) {
      float4 p0 = *(const float4*)(src + 0);
      float4 p1 = *(const float4*)(src + 4);
      float4 p2 = *(const float4*)(src + 8);
      float4 p3 = *(const float4*)(src + 12);
      v0[0] = (short)f2bf(p0.x); v0[1] = (short)f2bf(p0.y);
      v0[2] = (short)f2bf(p0.z); v0[3] = (short)f2bf(p0.w);
      v0[4] = (short)f2bf(p1.x); v0[5] = (short)f2bf(p1.y);
      v0[6] = (short)f2bf(p1.z); v0[7] = (short)f2bf(p1.w);
      v1[0] = (short)f2bf(p2.x); v1[1] = (short)f2bf(p2.y);
      v1[2] = (short)f2bf(p2.z); v1[3] = (short)f2bf(p2.w);
      v1[4] = (short)f2bf(p3.x); v1[5] = (short)f2bf(p3.y);
      v1[6] = (short)f2bf(p3.z); v1[7] = (short)f2bf(p3.w);
    }
    char* base = (char*)&Al[buf][0] + row * 512;
    const int sw = (row & 7) << 4;
    *(bf16x8*)(base + ((seg * 32 +  0) ^ sw)) = v0;
    *(bf16x8*)(base + ((seg * 32 + 16) ^ sw)) = v1;
  };

  stageA(0, b);
  __syncthreads();

  const int4* src4 = (const int4*)ei;
  const int4* dst4 = (const int4*)(ei + NEDGES);
  const int n4 = NEDGES / 4;

  int nc = 0;
  for (int c = b; c < NCHUNK; c += GEMMB, ++nc) {
    const int cur = nc & 1;
    if (c + GEMMB < NCHUNK) stageA(cur ^ 1, c + GEMMB);

    // embedded CSR fill (covers all edges in nc=0,1; hides under MFMA)
    if (nc < 2) {
      int i = nc * (GEMMB * CSRT) + b * CSRT + t;
      if (i < n4) {
        int4 s = src4[i];
        int4 d = dst4[i];
        esrc[atomicAdd(&cursor[d.x], 1)] = s.x;
        esrc[atomicAdd(&cursor[d.y], 1)] = s.y;
        esrc[atomicAdd(&cursor[d.z], 1)] = s.z;
        esrc[atomicAdd(&cursor[d.w], 1)] = s.w;
      }
    }

    // compute: full K=256, 8 k-slices x 4 n = 32 MFMA
    f32x4 acc[4] = {};
    const int arow_f = wr * 16 + (lane & 15);
    const int asw = (arow_f & 7) << 4;
#pragma unroll
    for (int ks = 0; ks < 8; ++ks) {
      const int koff = ks * 64 + ((lane >> 4) * 16);
      bf16x8 af = *(const bf16x8*)((char*)&Al[cur][0] + arow_f * 512 + (koff ^ asw));
#pragma unroll
      for (int n = 0; n < 4; ++n) {
        int nr = wc * 64 + n * 16 + (lane & 15);
        bf16x8 bfr = *(const bf16x8*)((char*)Bl + (size_t)nr * 512 + (koff ^ ((nr & 7) << 4)));
        acc[n] = __builtin_amdgcn_mfma_f32_16x16x32_bf16(af, bfr, acc[n], 0, 0, 0);
      }
    }

    // epilogue: bf16 h + col-stat accumulation
#pragma unroll
    for (int n = 0; n < 4; ++n) {
      int col = wc * 64 + n * 16 + (lane & 15);
      float s = 0.f, q = 0.f;
#pragma unroll
      for (int r = 0; r < 4; ++r) {
        int row = c * 32 + wr * 16 + (lane >> 4) * 4 + r;
        float v = acc[n][r];
        s += v; q += v * v;
        if (row < NNODES) hbf[(size_t)row * 256 + col] = f2bf(v);
      }
      spart[n] += s; qpart[n] += q;
    }
    __syncthreads();
  }

  // fold register col-stats (1 atomic/col/block)
#pragma unroll
  for (int n = 0; n < 4; ++n) {
    float s = spart[n], q = qpart[n];
    s += __shfl_xor(s, 16); s += __shfl_xor(s, 32);
    q += __shfl_xor(q, 16); q += __shfl_xor(q, 32);
    if (lane < 16) {
      int col = wc * 64 + n * 16 + lane;
      atomicAdd(&colsum[col], s);
      atomicAdd(&colsumsq[col], q);
    }
  }
}

// ---------------------------------------------------------------------------
// PERSISTENT GEMM2 (round-14 proven): out = relu((1-b)*S + b*(S@W_op)),
// S residual read back from the A LDS tile.
// ---------------------------------------------------------------------------
__global__ __launch_bounds__(512) void gemm2_k(
    const unsigned short* __restrict__ Ain,   // supp bf16
    const unsigned short* __restrict__ Bt,    // wop_t
    float* __restrict__ Cout,
    int M) {
  __shared__ __align__(16) unsigned short Bl[256 * 256];
  __shared__ __align__(16) unsigned short Al[2][32 * 256];

  const int t    = threadIdx.x;
  const int lane = t & 63;
  const int wid  = t >> 6;
  const int wr   = wid >> 2;
  const int wc   = wid & 3;

  {
    const int lrow = lane >> 5, lchk = lane & 31;
#pragma unroll
    for (int c = 0; c < 16; ++c) {
      int issue = wid * 16 + c;
      int row = issue * 2 + lrow;
      int srcoff = (lchk * 16) ^ ((row & 7) << 4);
      const char* g = (const char*)Bt + (size_t)row * 512 + srcoff;
      char* l = (char*)Bl + issue * 1024 + lane * 16;
      __builtin_amdgcn_global_load_lds((gu32*)g, (lu32*)l, 16, 0, 0);
    }
  }

  auto stageA = [&](int buf, int chunk) {
    const int lrow = lane >> 5, lchk = lane & 31;
#pragma unroll
    for (int c = 0; c < 2; ++c) {
      int issue = wid * 2 + c;
      int row = issue * 2 + lrow;
      int srcoff = (lchk * 16) ^ ((row & 7) << 4);
      const char* g = (const char*)Ain + (size_t)(chunk * 32 + row) * 512 + srcoff;
      char* l = (char*)&Al[buf][0] + issue * 1024 + lane * 16;
      __builtin_amdgcn_global_load_lds((gu32*)g, (lu32*)l, 16, 0, 0);
    }
  };

  stageA(0, blockIdx.x);
  __syncthreads();

  int nc = 0;
  for (int c = blockIdx.x; c < NCHUNK; c += GEMMB, ++nc) {
    const int cur = nc & 1;
    if (c + GEMMB < NCHUNK) stageA(cur ^ 1, c + GEMMB);

    f32x4 acc[4] = {};
    const int arow_f = wr * 16 + (lane & 15);
    const int asw = (arow_f & 7) << 4;
#pragma unroll
    for (int ks = 0; ks < 8; ++ks) {
      const int koff = ks * 64 + ((lane >> 4) * 16);
      bf16x8 af = *(const bf16x8*)((char*)&Al[cur][0] + arow_f * 512 + (koff ^ asw));
#pragma unroll
      for (int n = 0; n < 4; ++n) {
        int nr = wc * 64 + n * 16 + (lane & 15);
        bf16x8 bfr = *(const bf16x8*)((char*)Bl + (size_t)nr * 512 + (koff ^ ((nr & 7) << 4)));
        acc[n] = __builtin_amdgcn_mfma_f32_16x16x32_bf16(af, bfr, acc[n], 0, 0, 0);
      }
    }

#pragma unroll
    for (int n = 0; n < 4; ++n) {
      int col = wc * 64 + n * 16 + (lane & 15);
#pragma unroll
      for (int r = 0; r < 4; ++r) {
        int rl = wr * 16 + (lane >> 4) * 4 + r;
        int row = c * 32 + rl;
        if (row < M) {
          unsigned short sv = *(const unsigned short*)
              ((char*)&Al[cur][0] + rl * 512 + ((col * 2) ^ ((rl & 7) << 4)));
          Cout[(size_t)row * 256 + col] =
              fmaxf((1.f - kBeta) * bf2f(sv) + kBeta * acc[n][r], 0.f);
        }
      }
    }
    __syncthreads();
  }
}

// ---------------------------------------------------------------------------
// Gather-sum + fused BN-finalize/BN/ReLU + GCNII support mix (round-10 proven)
// ---------------------------------------------------------------------------
__global__ __launch_bounds__(256) void agg_bn_support_k(
    const unsigned short* __restrict__ hb,
    const int* __restrict__ rowptr,
    const int* __restrict__ esrc,
    const float* __restrict__ x0,
    const float* __restrict__ colsum,
    const float* __restrict__ colsumsq,
    const float* __restrict__ gamma,
    const float* __restrict__ beta_bn,
    unsigned short* __restrict__ supp_bf) {
  __shared__ float s_sc[256], s_sh[256];
  {
    int j = threadIdx.x;
    float inv_n = 1.0f / (float)NNODES;
    float mu  = colsum[j] * inv_n;
    float var = colsumsq[j] * inv_n - mu * mu;
    float rstd = rsqrtf(var + kBnEps);
    float g = gamma[j] * rstd;
    s_sc[j] = g;
    s_sh[j] = beta_bn[j] - mu * g;
  }
  __syncthreads();

  const int hw   = threadIdx.x >> 5;
  const int lane = threadIdx.x & 31;
  const int d    = blockIdx.x * 8 + hw;
  const int off  = lane * 8;

  float sc[8], sh[8];
  *(float4*)&sc[0] = *(const float4*)(s_sc + off);
  *(float4*)&sc[4] = *(const float4*)(s_sc + off + 4);
  *(float4*)&sh[0] = *(const float4*)(s_sh + off);
  *(float4*)&sh[4] = *(const float4*)(s_sh + off + 4);

  const int beg = rowptr[d];
  const int end = rowptr[d + 1];
  float acc[8] = {0.f, 0.f, 0.f, 0.f, 0.f, 0.f, 0.f, 0.f};

  for (int bb = beg; bb < end; bb += 32) {
    int cnt = end - bb; if (cnt > 32) cnt = 32;
    int myi = esrc[bb + ((lane < cnt) ? lane : 0)];
    int u = 0;
    for (; u + 3 < cnt; u += 4) {
      int s0 = __shfl(myi, u, 32),     s1 = __shfl(myi, u + 1, 32);
      int s2 = __shfl(myi, u + 2, 32), s3 = __shfl(myi, u + 3, 32);
      bf16x8 v0 = *(const bf16x8*)(hb + (size_t)s0 * HIDDIM + off);
      bf16x8 v1 = *(const bf16x8*)(hb + (size_t)s1 * HIDDIM + off);
      bf16x8 v2 = *(const bf16x8*)(hb + (size_t)s2 * HIDDIM + off);
      bf16x8 v3 = *(const bf16x8*)(hb + (size_t)s3 * HIDDIM + off);
#pragma unroll
      for (int j = 0; j < 8; ++j) {
        acc[j] += fmaxf(fmaf(bf2f((unsigned short)v0[j]), sc[j], sh[j]), 0.f)
                + fmaxf(fmaf(bf2f((unsigned short)v1[j]), sc[j], sh[j]), 0.f)
                + fmaxf(fmaf(bf2f((unsigned short)v2[j]), sc[j], sh[j]), 0.f)
                + fmaxf(fmaf(bf2f((unsigned short)v3[j]), sc[j], sh[j]), 0.f);
      }
    }
    for (; u < cnt; ++u) {
      int s0 = __shfl(myi, u, 32);
      bf16x8 v0 = *(const bf16x8*)(hb + (size_t)s0 * HIDDIM + off);
#pragma unroll
      for (int j = 0; j < 8; ++j)
        acc[j] += fmaxf(fmaf(bf2f((unsigned short)v0[j]), sc[j], sh[j]), 0.f);
    }
  }

  bf16x8 vd = *(const bf16x8*)(hb + (size_t)d * HIDDIM + off);
  f32x4 xa = __builtin_nontemporal_load((const f32x4*)(x0 + (size_t)d * HIDDIM + off));
  f32x4 xb = __builtin_nontemporal_load((const f32x4*)(x0 + (size_t)d * HIDDIM + off + 4));
  float xs[8] = {xa.x, xa.y, xa.z, xa.w, xb.x, xb.y, xb.z, xb.w};
  bf16x8 o;
#pragma unroll
  for (int j = 0; j < 8; ++j) {
    float hv = fmaxf(fmaf(bf2f((unsigned short)vd[j]), sc[j], sh[j]), 0.f);
    o[j] = (short)f2bf((1.f - kAlpha) * (hv + acc[j]) + kAlpha * xs[j]);
  }
  __builtin_nontemporal_store(o, (bf16x8*)(supp_bf + (size_t)d * HIDDIM + off));
}

// ---------------------------------------------------------------------------
extern "C" void kernel_launch(void* const* d_in, const int* in_sizes, int n_in,
                              void* d_out, int out_size, void* d_ws, size_t ws_size,
                              hipStream_t stream) {
  // inputs: s0, s1, x_0, W_pre, gamma, beta_bn, W_op, edge_index, drop_prob, training
  const float* s1    = (const float*)d_in[1];
  const float* x0    = (const float*)d_in[2];
  const float* W_pre = (const float*)d_in[3];
  const float* gamma = (const float*)d_in[4];
  const float* betab = (const float*)d_in[5];
  const float* W_op  = (const float*)d_in[6];
  const int*   ei    = (const int*)d_in[7];
  float* out = (float*)d_out;

  const size_t NH = (size_t)NNODES * HIDDIM;            // 12.8M elements
  unsigned short* hbf   = (unsigned short*)d_ws;        // 25.6 MB (raw bf16 h)
  unsigned short* supbf = hbf + NH;                     // 25.6 MB
  float* colsum   = (float*)(supbf + NH);               // 256
  float* colsumsq = colsum + HIDDIM;
  unsigned short* wpre_t = (unsigned short*)(colsumsq + HIDDIM);  // 128 KB
  unsigned short* wop_t  = wpre_t + 65536;              // 128 KB
  int* deg      = (int*)(wop_t + 65536);                // 50000
  int* cursor   = deg + NNODES;                         // 50000
  int* rowptr   = cursor + NNODES;                      // 50001
  int* esrc     = rowptr + (NNODES + 1);                // 800000
  int* blocksum = esrc + NEDGES;                        // 256
  int* barc     = blocksum + 256;                       // 4 barrier counters

  // zero barrier counters (graph node; deterministic per call)
  hipMemsetAsync(barc, 0, 4 * sizeof(int), stream);

  // weight transposes + BN-stat zero
  prep_k<<<512, 256, 0, stream>>>(W_pre, W_op, wpre_t, wop_t, colsum, colsumsq);

  // fused CSR build + GEMM1 (+fill embedded, +BN stats)
  csr_gemm1_k<<<GEMMB, CSRT, 0, stream>>>(s1, wpre_t, hbf, colsum, colsumsq,
                                          ei, deg, rowptr, cursor, esrc,
                                          blocksum, barc);

  // gather + fused BN-finalize/BN/ReLU + support mix
  agg_bn_support_k<<<(NNODES + 7) / 8, 256, 0, stream>>>(hbf, rowptr, esrc, x0,
                                                         colsum, colsumsq, gamma, betab,
                                                         supbf);

  // GEMM2 + GCNII epilogue
  gemm2_k<<<GEMMB, CSRT, 0, stream>>>(supbf, wop_t, out, NNODES);
}

// Round 16
// 222.360 us; speedup vs baseline: 1.1974x; 1.1974x over previous
//
#include <hip/hip_runtime.h>

#define NNODES 50000
#define NEDGES 800000
#define HIDDIM 256
#define NB_SCAN 196   // ceil(NNODES/256)
#define NCHUNK  1563  // ceil(NNODES/32)
#define GEMMB   256   // persistent GEMM blocks (1 per CU)

constexpr float kAlpha = 0.1f;
constexpr float kBnEps = 1e-5f;
constexpr float kBeta  = 0.40546510810816438198f;   // log(1.5)

typedef __attribute__((ext_vector_type(8))) short  bf16x8;   // 8 bf16 in 4 VGPRs
typedef __attribute__((ext_vector_type(4))) float  f32x4;

typedef __attribute__((address_space(1))) const unsigned int gu32;  // global
typedef __attribute__((address_space(3))) unsigned int       lu32;  // LDS

static __device__ __forceinline__ unsigned short f2bf(float f) {
  unsigned u = __float_as_uint(f);
  u = (u + 0x7FFFu + ((u >> 16) & 1u)) >> 16;      // RTNE
  return (unsigned short)u;
}
static __device__ __forceinline__ float bf2f(unsigned short h) {
  return __uint_as_float(((unsigned)h) << 16);
}

// ---------------------------------------------------------------------------
// prep (blocks 0..511): weight transposes + zero BN stats
// hist (blocks 512..): degree histogram over edge dst (int4 vectorized)
// deg[] zeroed by a preceding hipMemsetAsync.
// ---------------------------------------------------------------------------
__global__ __launch_bounds__(256) void prep_hist_k(const float* __restrict__ W_pre,
                                                   const float* __restrict__ W_op,
                                                   unsigned short* __restrict__ wpre_t,
                                                   unsigned short* __restrict__ wop_t,
                                                   float* __restrict__ colsum,
                                                   float* __restrict__ colsumsq,
                                                   const int* __restrict__ ei,
                                                   int* __restrict__ deg) {
  const int b = blockIdx.x, t = threadIdx.x;
  if (b < 256) {
    wpre_t[b * 256 + t] = f2bf(W_pre[t * 256 + b]);
    if (b == 0) { colsum[t] = 0.f; colsumsq[t] = 0.f; }
  } else if (b < 512) {
    int n = b - 256;
    wop_t[n * 256 + t] = f2bf(W_op[t * 256 + n]);
  } else {
    const int4* dst4 = (const int4*)(ei + NEDGES);
    const int n4 = NEDGES / 4;
    const int nb = gridDim.x - 512;
    for (int i = (b - 512) * 256 + t; i < n4; i += nb * 256) {
      int4 d = dst4[i];
      atomicAdd(&deg[d.x], 1);
      atomicAdd(&deg[d.y], 1);
      atomicAdd(&deg[d.z], 1);
      atomicAdd(&deg[d.w], 1);
    }
  }
}

// ---------------------------------------------------------------------------
// CSR scan + fill (round-10/14 proven versions)
// ---------------------------------------------------------------------------
__global__ __launch_bounds__(256) void scanA_k(const int* __restrict__ deg,
                                               int* __restrict__ rowptr,
                                               int* __restrict__ blocksum) {
  __shared__ int sh[256];
  const int t = threadIdx.x;
  const int idx = blockIdx.x * 256 + t;
  int v = (idx < NNODES) ? deg[idx] : 0;
  sh[t] = v;
  __syncthreads();
  for (int off = 1; off < 256; off <<= 1) {
    int x = (t >= off) ? sh[t - off] : 0;
    __syncthreads();
    sh[t] += x;
    __syncthreads();
  }
  if (idx < NNODES) rowptr[idx] = sh[t] - v;      // exclusive within block
  if (t == 255) blocksum[blockIdx.x] = sh[255];
}

__global__ __launch_bounds__(256) void scanB_k(const int* __restrict__ blocksum,
                                               int* __restrict__ blockoff,
                                               int* __restrict__ rowptr) {
  __shared__ int sh[256];
  const int t = threadIdx.x;
  int v = (t < NB_SCAN) ? blocksum[t] : 0;
  sh[t] = v;
  __syncthreads();
  for (int off = 1; off < 256; off <<= 1) {
    int x = (t >= off) ? sh[t - off] : 0;
    __syncthreads();
    sh[t] += x;
    __syncthreads();
  }
  blockoff[t] = sh[t] - v;                        // exclusive block offset
  if (t == 255) rowptr[NNODES] = sh[255];         // grand total (=NEDGES)
}

__global__ __launch_bounds__(256) void scanC_k(int* __restrict__ rowptr,
                                               const int* __restrict__ blockoff,
                                               int* __restrict__ cursor) {
  const int idx = blockIdx.x * 256 + threadIdx.x;
  if (idx < NNODES) {
    int rp = rowptr[idx] + blockoff[blockIdx.x];
    rowptr[idx] = rp;
    cursor[idx] = rp;
  }
}

__global__ __launch_bounds__(256) void fill_k(const int* __restrict__ ei,
                                              int* __restrict__ cursor,
                                              int* __restrict__ esrc) {
  const int4* src4 = (const int4*)ei;
  const int4* dst4 = (const int4*)(ei + NEDGES);
  const int n4 = NEDGES / 4;
  int stride = gridDim.x * blockDim.x;
  for (int i = blockIdx.x * blockDim.x + threadIdx.x; i < n4; i += stride) {
    int4 s = src4[i];
    int4 d = dst4[i];
    esrc[atomicAdd(&cursor[d.x], 1)] = s.x;
    esrc[atomicAdd(&cursor[d.y], 1)] = s.y;
    esrc[atomicAdd(&cursor[d.z], 1)] = s.z;
    esrc[atomicAdd(&cursor[d.w], 1)] = s.w;
  }
}

// ---------------------------------------------------------------------------
// PERSISTENT bf16 MFMA GEMM (round-14 proven structure): C = A @ B.
// 256 blocks (1/CU), 512 threads (8 waves as 2 row-groups x 4 col-groups).
// B (128 KB) lives in LDS; A streams through 2x16KB double buffer in 32-row
// chunks; one barrier per chunk; full K=256 per chunk (32 MFMA/wave).
// MODE 0: A fp32, FLAT-COALESCED reg-stage + convert (each wave load = one
//         contiguous 1-KB row segment); C bf16 + col stats (reg-accumulated).
// MODE 1: A bf16 via global_load_lds; S residual read back from LDS;
//         C fp32 = relu((1-beta)*S + beta*(A@B)).
// ---------------------------------------------------------------------------
template<int MODE>
__global__ __launch_bounds__(512) void gemm_persist_k(
    const void* __restrict__ Ain,
    const unsigned short* __restrict__ Bt,   // [256][256] bf16, Bt[n][k]
    void* __restrict__ Cout,                 // MODE0: bf16; MODE1: float
    float* __restrict__ colsum,
    float* __restrict__ colsumsq,
    int M) {
  __shared__ __align__(16) unsigned short Bl[256 * 256];   // 128 KB, 512 B rows
  __shared__ __align__(16) unsigned short Al[2][32 * 256]; // 2 x 16 KB

  const int t    = threadIdx.x;          // 0..511
  const int lane = t & 63;
  const int wid  = t >> 6;               // 0..7
  const int wr   = wid >> 2;             // row group 0/1 (16 rows each)
  const int wc   = wid & 3;              // col group 0..3 (64 cols each)

  // ---- B preload: 128 issues x 1 KB (2 rows each), 16 per wave ----
  {
    const int lrow = lane >> 5;          // 0..1
    const int lchk = lane & 31;          // 16B chunk in 512-B row
#pragma unroll
    for (int c = 0; c < 16; ++c) {
      int issue = wid * 16 + c;          // 0..127
      int row = issue * 2 + lrow;        // 0..255
      int srcoff = (lchk * 16) ^ ((row & 7) << 4);
      const char* g = (const char*)Bt + (size_t)row * 512 + srcoff;
      char* l = (char*)Bl + issue * 1024 + lane * 16;
      __builtin_amdgcn_global_load_lds((gu32*)g, (lu32*)l, 16, 0, 0);
    }
  }

  float spart[4] = {0.f, 0.f, 0.f, 0.f};
  float qpart[4] = {0.f, 0.f, 0.f, 0.f};

  auto stageA = [&](int buf, int chunk) {
    const int r0 = chunk * 32;
    if (MODE == 0) {
      // flat-coalesced: float4 #e of the 32x256 chunk; wave = 1 KB contiguous
#pragma unroll
      for (int s = 0; s < 4; ++s) {
        int e   = s * 512 + t;           // 0..2047
        int row = e >> 6;                // 0..31
        int c4  = e & 63;                // float4 within row
        int arow = r0 + row;
        float4 p = make_float4(0.f, 0.f, 0.f, 0.f);
        if (arow < M) p = *(const float4*)((const float*)Ain + (size_t)arow * 256 + c4 * 4);
        short4 v;
        v.x = (short)f2bf(p.x); v.y = (short)f2bf(p.y);
        v.z = (short)f2bf(p.z); v.w = (short)f2bf(p.w);
        char* base = (char*)&Al[buf][0] + row * 512;
        *(short4*)(base + ((c4 * 8) ^ ((row & 7) << 4))) = v;
      }
    } else {
      // 16 issues x 1 KB (2 rows each), 2 per wave
      const int lrow = lane >> 5;
      const int lchk = lane & 31;
#pragma unroll
      for (int c = 0; c < 2; ++c) {
        int issue = wid * 2 + c;         // 0..15
        int row = issue * 2 + lrow;      // 0..31
        int srcoff = (lchk * 16) ^ ((row & 7) << 4);
        const char* g = (const char*)Ain + (size_t)(r0 + row) * 512 + srcoff;
        char* l = (char*)&Al[buf][0] + issue * 1024 + lane * 16;
        __builtin_amdgcn_global_load_lds((gu32*)g, (lu32*)l, 16, 0, 0);
      }
    }
  };

  stageA(0, blockIdx.x);
  __syncthreads();                       // B + first A ready

  int nc = 0;
  for (int c = blockIdx.x; c < NCHUNK; c += GEMMB, ++nc) {
    const int cur = nc & 1;
    const int cn = c + GEMMB;
    if (cn < NCHUNK) stageA(cur ^ 1, cn);   // next chunk flies under MFMA

    // ---- compute: full K=256, 8 k-slices x 4 n = 32 MFMA ----
    f32x4 acc[4] = {};
    const int arow_f = wr * 16 + (lane & 15);
    const int asw = (arow_f & 7) << 4;
#pragma unroll
    for (int ks = 0; ks < 8; ++ks) {
      const int koff = ks * 64 + ((lane >> 4) * 16);
      bf16x8 af = *(const bf16x8*)((char*)&Al[cur][0] + arow_f * 512 + (koff ^ asw));
#pragma unroll
      for (int n = 0; n < 4; ++n) {
        int nr = wc * 64 + n * 16 + (lane & 15);
        bf16x8 bfr = *(const bf16x8*)((char*)Bl + (size_t)nr * 512 + (koff ^ ((nr & 7) << 4)));
        acc[n] = __builtin_amdgcn_mfma_f32_16x16x32_bf16(af, bfr, acc[n], 0, 0, 0);
      }
    }

    // ---- epilogue (C/D layout: col=lane&15, row=(lane>>4)*4+r) ----
    if (MODE == 0) {
      unsigned short* hC = (unsigned short*)Cout;
#pragma unroll
      for (int n = 0; n < 4; ++n) {
        int col = wc * 64 + n * 16 + (lane & 15);
        float s = 0.f, q = 0.f;
#pragma unroll
        for (int r = 0; r < 4; ++r) {
          int row = c * 32 + wr * 16 + (lane >> 4) * 4 + r;
          float v = acc[n][r];
          s += v; q += v * v;
          if (row < M) hC[(size_t)row * 256 + col] = f2bf(v);
        }
        spart[n] += s; qpart[n] += q;
      }
    } else {
      float* oC = (float*)Cout;
#pragma unroll
      for (int n = 0; n < 4; ++n) {
        int col = wc * 64 + n * 16 + (lane & 15);
#pragma unroll
        for (int r = 0; r < 4; ++r) {
          int rl = wr * 16 + (lane >> 4) * 4 + r;
          int row = c * 32 + rl;
          if (row < M) {
            // residual S == A row, still resident in Al[cur]
            unsigned short sv = *(const unsigned short*)
                ((char*)&Al[cur][0] + rl * 512 + ((col * 2) ^ ((rl & 7) << 4)));
            oC[(size_t)row * 256 + col] =
                fmaxf((1.f - kBeta) * bf2f(sv) + kBeta * acc[n][r], 0.f);
          }
        }
      }
    }
    __syncthreads();   // drains next-chunk loads; protects Al[cur] for rewrite
  }

  // ---- MODE 0: fold register col-stats into global (1 atomic/col/block) ----
  if (MODE == 0) {
#pragma unroll
    for (int n = 0; n < 4; ++n) {
      float s = spart[n], q = qpart[n];
      s += __shfl_xor(s, 16); s += __shfl_xor(s, 32);
      q += __shfl_xor(q, 16); q += __shfl_xor(q, 32);
      if (lane < 16) {
        int col = wc * 64 + n * 16 + lane;
        atomicAdd(&colsum[col], s);
        atomicAdd(&colsumsq[col], q);
      }
    }
  }
}

// ---------------------------------------------------------------------------
// Gather-sum + fused BN-finalize/BN/ReLU + GCNII support mix (proven).
// ---------------------------------------------------------------------------
__global__ __launch_bounds__(256) void agg_bn_support_k(
    const unsigned short* __restrict__ hb,
    const int* __restrict__ rowptr,
    const int* __restrict__ esrc,
    const float* __restrict__ x0,
    const float* __restrict__ colsum,
    const float* __restrict__ colsumsq,
    const float* __restrict__ gamma,
    const float* __restrict__ beta_bn,
    unsigned short* __restrict__ supp_bf) {
  __shared__ float s_sc[256], s_sh[256];
  {
    int j = threadIdx.x;
    float inv_n = 1.0f / (float)NNODES;
    float mu  = colsum[j] * inv_n;
    float var = colsumsq[j] * inv_n - mu * mu;
    float rstd = rsqrtf(var + kBnEps);
    float g = gamma[j] * rstd;
    s_sc[j] = g;
    s_sh[j] = beta_bn[j] - mu * g;
  }
  __syncthreads();

  const int hw   = threadIdx.x >> 5;
  const int lane = threadIdx.x & 31;
  const int d    = blockIdx.x * 8 + hw;
  const int off  = lane * 8;

  float sc[8], sh[8];
  *(float4*)&sc[0] = *(const float4*)(s_sc + off);
  *(float4*)&sc[4] = *(const float4*)(s_sc + off + 4);
  *(float4*)&sh[0] = *(const float4*)(s_sh + off);
  *(float4*)&sh[4] = *(const float4*)(s_sh + off + 4);

  const int beg = rowptr[d];
  const int end = rowptr[d + 1];
  float acc[8] = {0.f, 0.f, 0.f, 0.f, 0.f, 0.f, 0.f, 0.f};

  for (int bb = beg; bb < end; bb += 32) {
    int cnt = end - bb; if (cnt > 32) cnt = 32;
    int myi = esrc[bb + ((lane < cnt) ? lane : 0)];
    int u = 0;
    for (; u + 3 < cnt; u += 4) {
      int s0 = __shfl(myi, u, 32),     s1 = __shfl(myi, u + 1, 32);
      int s2 = __shfl(myi, u + 2, 32), s3 = __shfl(myi, u + 3, 32);
      bf16x8 v0 = *(const bf16x8*)(hb + (size_t)s0 * HIDDIM + off);
      bf16x8 v1 = *(const bf16x8*)(hb + (size_t)s1 * HIDDIM + off);
      bf16x8 v2 = *(const bf16x8*)(hb + (size_t)s2 * HIDDIM + off);
      bf16x8 v3 = *(const bf16x8*)(hb + (size_t)s3 * HIDDIM + off);
#pragma unroll
      for (int j = 0; j < 8; ++j) {
        acc[j] += fmaxf(fmaf(bf2f((unsigned short)v0[j]), sc[j], sh[j]), 0.f)
                + fmaxf(fmaf(bf2f((unsigned short)v1[j]), sc[j], sh[j]), 0.f)
                + fmaxf(fmaf(bf2f((unsigned short)v2[j]), sc[j], sh[j]), 0.f)
                + fmaxf(fmaf(bf2f((unsigned short)v3[j]), sc[j], sh[j]), 0.f);
      }
    }
    for (; u < cnt; ++u) {
      int s0 = __shfl(myi, u, 32);
      bf16x8 v0 = *(const bf16x8*)(hb + (size_t)s0 * HIDDIM + off);
#pragma unroll
      for (int j = 0; j < 8; ++j)
        acc[j] += fmaxf(fmaf(bf2f((unsigned short)v0[j]), sc[j], sh[j]), 0.f);
    }
  }

  bf16x8 vd = *(const bf16x8*)(hb + (size_t)d * HIDDIM + off);
  f32x4 xa = __builtin_nontemporal_load((const f32x4*)(x0 + (size_t)d * HIDDIM + off));
  f32x4 xb = __builtin_nontemporal_load((const f32x4*)(x0 + (size_t)d * HIDDIM + off + 4));
  float xs[8] = {xa.x, xa.y, xa.z, xa.w, xb.x, xb.y, xb.z, xb.w};
  bf16x8 o;
#pragma unroll
  for (int j = 0; j < 8; ++j) {
    float hv = fmaxf(fmaf(bf2f((unsigned short)vd[j]), sc[j], sh[j]), 0.f);
    o[j] = (short)f2bf((1.f - kAlpha) * (hv + acc[j]) + kAlpha * xs[j]);
  }
  __builtin_nontemporal_store(o, (bf16x8*)(supp_bf + (size_t)d * HIDDIM + off));
}

// ---------------------------------------------------------------------------
extern "C" void kernel_launch(void* const* d_in, const int* in_sizes, int n_in,
                              void* d_out, int out_size, void* d_ws, size_t ws_size,
                              hipStream_t stream) {
  // inputs: s0, s1, x_0, W_pre, gamma, beta_bn, W_op, edge_index, drop_prob, training
  const float* s1    = (const float*)d_in[1];
  const float* x0    = (const float*)d_in[2];
  const float* W_pre = (const float*)d_in[3];
  const float* gamma = (const float*)d_in[4];
  const float* betab = (const float*)d_in[5];
  const float* W_op  = (const float*)d_in[6];
  const int*   ei    = (const int*)d_in[7];
  float* out = (float*)d_out;

  const size_t NH = (size_t)NNODES * HIDDIM;            // 12.8M elements
  unsigned short* hbf   = (unsigned short*)d_ws;        // 25.6 MB (raw bf16 h)
  unsigned short* supbf = hbf + NH;                     // 25.6 MB
  float* colsum   = (float*)(supbf + NH);               // 256
  float* colsumsq = colsum + HIDDIM;
  unsigned short* wpre_t = (unsigned short*)(colsumsq + HIDDIM);  // 128 KB
  unsigned short* wop_t  = wpre_t + 65536;              // 128 KB
  int* deg      = (int*)(wop_t + 65536);                // 50000
  int* cursor   = deg + NNODES;                         // 50000
  int* rowptr   = cursor + NNODES;                      // 50001
  int* esrc     = rowptr + (NNODES + 1);                // 800000
  int* blocksum = esrc + NEDGES;                        // 256
  int* blockoff = blocksum + 256;                       // 256

  // zero deg for the fused histogram
  hipMemsetAsync(deg, 0, NNODES * sizeof(int), stream);

  // weight transposes + BN-stat zero + degree histogram (fused)
  prep_hist_k<<<1024, 256, 0, stream>>>(W_pre, W_op, wpre_t, wop_t,
                                        colsum, colsumsq, ei, deg);

  // CSR scan + fill
  scanA_k<<<NB_SCAN, 256, 0, stream>>>(deg, rowptr, blocksum);
  scanB_k<<<1, 256, 0, stream>>>(blocksum, blockoff, rowptr);
  scanC_k<<<NB_SCAN, 256, 0, stream>>>(rowptr, blockoff, cursor);
  fill_k<<<1024, 256, 0, stream>>>(ei, cursor, esrc);

  // GEMM1 (persistent, B-in-LDS): fp32 A -> raw bf16 h + BN stats
  gemm_persist_k<0><<<GEMMB, 512, 0, stream>>>(s1, wpre_t, hbf, colsum, colsumsq, NNODES);

  // gather + fused BN-finalize/BN/ReLU + support mix
  agg_bn_support_k<<<(NNODES + 7) / 8, 256, 0, stream>>>(hbf, rowptr, esrc, x0,
                                                         colsum, colsumsq, gamma, betab,
                                                         supbf);

  // GEMM2 (persistent): supp @ W_op + GCNII epilogue (S read from LDS)
  gemm_persist_k<1><<<GEMMB, 512, 0, stream>>>(supbf, wop_t, out, nullptr, nullptr, NNODES);
}